// Round 10
// baseline (9762.959 us; speedup 1.0000x reference)
//
#include <hip/hip_runtime.h>
#include <hip/hip_bf16.h>

#define T_STEPS 512
#define BATCH   256
#define DIM     256
#define HID     256
#define DEPTH   4    // X_proj ring depth (power of 2)

using bf16x8  = __attribute__((ext_vector_type(8))) __bf16;
using bf16x4  = __attribute__((ext_vector_type(4))) __bf16;
using floatx4 = __attribute__((ext_vector_type(4))) float;
typedef unsigned long long u64;
typedef unsigned int u32;

__device__ __forceinline__ float sigf(float x)   { return 1.0f / (1.0f + __expf(-x)); }
__device__ __forceinline__ float tanh_f(float x) { return 1.0f - 2.0f / (1.0f + __expf(2.0f * x)); }

__device__ __forceinline__ bf16x8 cvt8(const float* p) {
  floatx4 a = *(const floatx4*)p;
  floatx4 b = *(const floatx4*)(p + 4);
  bf16x8 r;
  r[0]=(__bf16)a[0]; r[1]=(__bf16)a[1]; r[2]=(__bf16)a[2]; r[3]=(__bf16)a[3];
  r[4]=(__bf16)b[0]; r[5]=(__bf16)b[1]; r[6]=(__bf16)b[2]; r[7]=(__bf16)b[3];
  return r;
}
__device__ __forceinline__ u32 f2bf(float f) {
  union { float f; u32 u; } v; v.f = f;
  u32 lsb = (v.u >> 16) & 1;
  return (v.u + 0x7fff + lsb) >> 16;
}
__device__ __forceinline__ float bf2f(u32 u) {
  union { u32 u; float f; } v; v.u = (u & 0xffffu) << 16; return v.f;
}

// zero flags + ALL ring tags (first call runs on unpoisoned ws; stale tags
// could alias valid ones, so wipe every launch — deterministic, ~10 us)
__global__ void init_ws(int* __restrict__ flg, u64* __restrict__ ring) {
  const size_t idx = (size_t)blockIdx.x * 256 + threadIdx.x;
  if (idx < 512) flg[idx] = 0;
  for (size_t i = idx; i < 16ull * DEPTH * 8192; i += (size_t)gridDim.x * 256)
    ring[i] = 0ull;
}

// 32 WGs x 1024 thr. blockIdx = g + 16*role; group g = 16 batch rows.
// role 0: consumer — 16 waves, wave w owns h-cols [16w,16w+16) x 4 gates,
//   whh_r[4][8] = 128 VGPR/lane (the per-wave shape proven resident r3-r8).
//   The ENTIRE recurrence is in-WG: h exchange = LDS + s_barrier. Gates stay
//   in accumulators (C layout == cell layout) -> no LDS round-trip.
// role 1: producer — X_proj(t) = xi@W_ih^T + b, written as self-tagged
//   [tag|2xbf16] u64 ring packets, tid-aligned with the consumer.
__global__ __launch_bounds__(1024, 4) void lstm_w16(
    const float* __restrict__ x, const float* __restrict__ h0,
    const float* __restrict__ c0,
    const float* __restrict__ mask_x, const float* __restrict__ mask_h,
    const float* __restrict__ W_ih, const float* __restrict__ W_hh,
    const float* __restrict__ b_ih, const float* __restrict__ b_hh,
    const int* __restrict__ bs_g,
    float* __restrict__ out, float* __restrict__ hn_out, float* __restrict__ cn_out,
    int* __restrict__ flg, u64* __restrict__ ring) {

  const int tid  = threadIdx.x;
  const int g    = blockIdx.x & 15;
  const int role = blockIdx.x >> 4;
  const int row_base = g * 16;
  const int lane = tid & 63;
  const int w    = tid >> 6;          // wave 0..15
  const int l15  = lane & 15;
  const int l4   = lane >> 4;
  const int c_own = w * 16 + l15;     // this lane's h-column (0..255)

  __shared__ alignas(16) __bf16 s_ab[16 * 256];   // 8 KB swizzled activation tile
  __shared__ int s_bs[T_STEPS];
  for (int i = tid; i < T_STEPS; i += 1024) s_bs[i] = bs_g[i];
  __syncthreads();

  int* cflg   = flg + g * 32;
  u64* ring_g = ring + (size_t)g * (DEPTH * 8192);

  if (role == 1) {
    // ================= PRODUCER =================
    bf16x8 wih_r[4][8];
    #pragma unroll
    for (int q = 0; q < 4; ++q) {
      const size_t wr = (size_t)(q * HID + c_own) * DIM;
      #pragma unroll
      for (int m = 0; m < 8; ++m) wih_r[q][m] = cvt8(W_ih + wr + m * 32 + l4 * 8);
    }
    float bias[4];
    #pragma unroll
    for (int q = 0; q < 4; ++q)
      bias[q] = b_ih[q * HID + c_own] + b_hh[q * HID + c_own];

    const int srow = tid & 15;
    const int scb  = (tid >> 4) * 4;      // 64 col-groups x 4 cols
    const floatx4 mx = *(const floatx4*)(mask_x + (row_base + srow) * DIM + scb);
    const int soff = (srow * 512 + scb * 2) ^ ((srow & 7) << 4);

    floatx4 xv = *(const floatx4*)(x + (size_t)(row_base + srow) * DIM + scb);

    for (int t = 0; t < T_STEPS; ++t) {
      if (s_bs[t] <= row_base) break;
      if (t >= DEPTH) {                    // ring backpressure
        const int tgt = t - (DEPTH - 1);
        while (__hip_atomic_load(cflg, __ATOMIC_RELAXED, __HIP_MEMORY_SCOPE_AGENT) < tgt) {}
      }
      bf16x4 xb;
      #pragma unroll
      for (int e = 0; e < 4; ++e) xb[e] = (__bf16)(xv[e] * mx[e]);
      *(bf16x4*)((char*)s_ab + soff) = xb;
      asm volatile("s_waitcnt lgkmcnt(0)" ::: "memory");
      __builtin_amdgcn_s_barrier();

      floatx4 a0, a1, a2, a3;
      a0 = a1 = a2 = a3 = (floatx4)(0.0f);
      #pragma unroll
      for (int m = 0; m < 8; ++m) {
        const int ab = (l15 * 512 + l4 * 16 + m * 64) ^ ((l15 & 7) << 4);
        bf16x8 ax = *(const bf16x8*)((const char*)s_ab + ab);
        a0 = __builtin_amdgcn_mfma_f32_16x16x32_bf16(ax, wih_r[0][m], a0, 0, 0, 0);
        a1 = __builtin_amdgcn_mfma_f32_16x16x32_bf16(ax, wih_r[1][m], a1, 0, 0, 0);
        a2 = __builtin_amdgcn_mfma_f32_16x16x32_bf16(ax, wih_r[2][m], a2, 0, 0, 0);
        a3 = __builtin_amdgcn_mfma_f32_16x16x32_bf16(ax, wih_r[3][m], a3, 0, 0, 0);
      }
      if (t + 1 < T_STEPS) {
        const float* xp = x + ((size_t)(t + 1) * BATCH + row_base + srow) * DIM + scb;
        xv = *(const floatx4*)xp;
      }
      // self-tagged packets: e -> [tag|i|f], [tag|g|o]  (C row = l4*4+e, col = c_own)
      u64* rs = ring_g + (size_t)(t & (DEPTH - 1)) * 8192 + tid * 8;
      const u64 tag = (u32)(t + 1);
      #pragma unroll
      for (int e = 0; e < 4; ++e) {
        u64 w0 = tag | ((u64)f2bf(a0[e] + bias[0]) << 32) | ((u64)f2bf(a1[e] + bias[1]) << 48);
        u64 w1 = tag | ((u64)f2bf(a2[e] + bias[2]) << 32) | ((u64)f2bf(a3[e] + bias[3]) << 48);
        __hip_atomic_store(rs + e * 2,     w0, __ATOMIC_RELAXED, __HIP_MEMORY_SCOPE_AGENT);
        __hip_atomic_store(rs + e * 2 + 1, w1, __ATOMIC_RELAXED, __HIP_MEMORY_SCOPE_AGENT);
      }
      __builtin_amdgcn_s_barrier();        // WAR on s_ab only
    }
    return;
  }

  // ================= CONSUMER (whole recurrence in this WG) =================
  bf16x8 whh_r[4][8];                      // 128 VGPR/lane, all indices static
  #pragma unroll
  for (int q = 0; q < 4; ++q) {
    const size_t wr = (size_t)(q * HID + c_own) * HID;
    #pragma unroll
    for (int m = 0; m < 8; ++m) whh_r[q][m] = cvt8(W_hh + wr + m * 32 + l4 * 8);
  }
  float mh_c[4], h_[4], c_[4];
  #pragma unroll
  for (int e = 0; e < 4; ++e) {
    const int grow = row_base + l4 * 4 + e;
    mh_c[e] = mask_h[grow * HID + c_own];
    h_[e]   = h0[grow * HID + c_own];
    c_[e]   = c0[grow * HID + c_own];
  }

  // stage h(0): each thread writes its 4 cells (2B each, swizzled)
  #pragma unroll
  for (int e = 0; e < 4; ++e) {
    const int r = l4 * 4 + e;
    const int off = (r * 512 + c_own * 2) ^ ((r & 7) << 4);
    *(__bf16*)((char*)s_ab + off) = (__bf16)(h_[e] * mh_c[e]);
  }
  // issue ring loads for X_proj(0) (slot 0, tag 1); tag-checked in-loop
  u64 qv0, qv1, qv2, qv3, qv4, qv5, qv6, qv7;
  {
    const u64* rp = ring_g + tid * 8;
    qv0 = __hip_atomic_load(rp+0, __ATOMIC_RELAXED, __HIP_MEMORY_SCOPE_AGENT);
    qv1 = __hip_atomic_load(rp+1, __ATOMIC_RELAXED, __HIP_MEMORY_SCOPE_AGENT);
    qv2 = __hip_atomic_load(rp+2, __ATOMIC_RELAXED, __HIP_MEMORY_SCOPE_AGENT);
    qv3 = __hip_atomic_load(rp+3, __ATOMIC_RELAXED, __HIP_MEMORY_SCOPE_AGENT);
    qv4 = __hip_atomic_load(rp+4, __ATOMIC_RELAXED, __HIP_MEMORY_SCOPE_AGENT);
    qv5 = __hip_atomic_load(rp+5, __ATOMIC_RELAXED, __HIP_MEMORY_SCOPE_AGENT);
    qv6 = __hip_atomic_load(rp+6, __ATOMIC_RELAXED, __HIP_MEMORY_SCOPE_AGENT);
    qv7 = __hip_atomic_load(rp+7, __ATOMIC_RELAXED, __HIP_MEMORY_SCOPE_AGENT);
  }
  asm volatile("s_waitcnt lgkmcnt(0)" ::: "memory");
  __builtin_amdgcn_s_barrier();

  for (int t = 0; t < T_STEPS; ++t) {
    const int bszt = s_bs[t];
    if (bszt <= row_base) {                // group retired: zeros, no barriers
      #pragma unroll
      for (int e = 0; e < 4; ++e)
        out[(size_t)t * (BATCH * HID) + (row_base + l4 * 4 + e) * HID + c_own] = 0.0f;
      continue;
    }

    // h(t) @ W_hh^T : 4 gate tiles, K=256, accs ARE the cell gates
    floatx4 a0, a1, a2, a3;
    a0 = a1 = a2 = a3 = (floatx4)(0.0f);
    #pragma unroll
    for (int m = 0; m < 8; ++m) {
      const int ab = (l15 * 512 + l4 * 16 + m * 64) ^ ((l15 & 7) << 4);
      bf16x8 ah = *(const bf16x8*)((const char*)s_ab + ab);
      a0 = __builtin_amdgcn_mfma_f32_16x16x32_bf16(ah, whh_r[0][m], a0, 0, 0, 0);
      a1 = __builtin_amdgcn_mfma_f32_16x16x32_bf16(ah, whh_r[1][m], a1, 0, 0, 0);
      a2 = __builtin_amdgcn_mfma_f32_16x16x32_bf16(ah, whh_r[2][m], a2, 0, 0, 0);
      a3 = __builtin_amdgcn_mfma_f32_16x16x32_bf16(ah, whh_r[3][m], a3, 0, 0, 0);
    }

    // X_proj(t): tag-verify the preloaded packets (respins are rare)
    const u32 tg = (u32)(t + 1);
    {
      const u64* rp = ring_g + (size_t)(t & (DEPTH - 1)) * 8192 + tid * 8;
      while (!__all((int)(((u32)qv0==tg)&&((u32)qv1==tg)&&((u32)qv2==tg)&&((u32)qv3==tg)&&
                          ((u32)qv4==tg)&&((u32)qv5==tg)&&((u32)qv6==tg)&&((u32)qv7==tg)))) {
        qv0 = __hip_atomic_load(rp+0, __ATOMIC_RELAXED, __HIP_MEMORY_SCOPE_AGENT);
        qv1 = __hip_atomic_load(rp+1, __ATOMIC_RELAXED, __HIP_MEMORY_SCOPE_AGENT);
        qv2 = __hip_atomic_load(rp+2, __ATOMIC_RELAXED, __HIP_MEMORY_SCOPE_AGENT);
        qv3 = __hip_atomic_load(rp+3, __ATOMIC_RELAXED, __HIP_MEMORY_SCOPE_AGENT);
        qv4 = __hip_atomic_load(rp+4, __ATOMIC_RELAXED, __HIP_MEMORY_SCOPE_AGENT);
        qv5 = __hip_atomic_load(rp+5, __ATOMIC_RELAXED, __HIP_MEMORY_SCOPE_AGENT);
        qv6 = __hip_atomic_load(rp+6, __ATOMIC_RELAXED, __HIP_MEMORY_SCOPE_AGENT);
        qv7 = __hip_atomic_load(rp+7, __ATOMIC_RELAXED, __HIP_MEMORY_SCOPE_AGENT);
      }
    }

    // cell, fully in-register (C layout: row = l4*4+e, col = l15 -> c_own)
    floatx4 o4;
    {
      const float xi0 = bf2f((u32)(qv0 >> 32)), xf0 = bf2f((u32)(qv0 >> 48));
      const float xg0 = bf2f((u32)(qv1 >> 32)), xo0 = bf2f((u32)(qv1 >> 48));
      const float xi1 = bf2f((u32)(qv2 >> 32)), xf1 = bf2f((u32)(qv2 >> 48));
      const float xg1 = bf2f((u32)(qv3 >> 32)), xo1 = bf2f((u32)(qv3 >> 48));
      const float xi2 = bf2f((u32)(qv4 >> 32)), xf2 = bf2f((u32)(qv4 >> 48));
      const float xg2 = bf2f((u32)(qv5 >> 32)), xo2 = bf2f((u32)(qv5 >> 48));
      const float xi3 = bf2f((u32)(qv6 >> 32)), xf3 = bf2f((u32)(qv6 >> 48));
      const float xg3 = bf2f((u32)(qv7 >> 32)), xo3 = bf2f((u32)(qv7 >> 48));
      const float xi[4] = {xi0, xi1, xi2, xi3};
      const float xf[4] = {xf0, xf1, xf2, xf3};
      const float xg[4] = {xg0, xg1, xg2, xg3};
      const float xo[4] = {xo0, xo1, xo2, xo3};
      #pragma unroll
      for (int e = 0; e < 4; ++e) {
        const bool ract = (row_base + l4 * 4 + e) < bszt;
        const float iv = sigf(a0[e] + xi[e]);
        const float fv = sigf(a1[e] + xf[e]);
        const float gv = tanh_f(a2[e] + xg[e]);
        const float ov = sigf(a3[e] + xo[e]);
        const float cc = fv * c_[e] + iv * gv;
        const float hh = ov * tanh_f(cc);
        if (ract) { c_[e] = cc; h_[e] = hh; }
        o4[e] = ract ? hh : 0.0f;
      }
    }

    // out stores (fire; next tag-check is a full step away)
    #pragma unroll
    for (int e = 0; e < 4; ++e)
      out[(size_t)t * (BATCH * HID) + (row_base + l4 * 4 + e) * HID + c_own] = o4[e];

    __builtin_amdgcn_s_barrier();          // all waves done reading s_ab (h(t))

    const bool act_n = (t + 1 < T_STEPS) && (s_bs[t + 1] > row_base);
    if (act_n) {
      // stage h(t+1) (LDS only — THE recurrent exchange)
      #pragma unroll
      for (int e = 0; e < 4; ++e) {
        const int r = l4 * 4 + e;
        const int off = (r * 512 + c_own * 2) ^ ((r & 7) << 4);
        *(__bf16*)((char*)s_ab + off) = (__bf16)(h_[e] * mh_c[e]);
      }
      if (tid == 0)
        __hip_atomic_store(cflg, t + 1, __ATOMIC_RELAXED, __HIP_MEMORY_SCOPE_AGENT);
      // issue ring loads for X_proj(t+1) (consumed next iteration)
      const u64* rp = ring_g + (size_t)((t + 1) & (DEPTH - 1)) * 8192 + tid * 8;
      qv0 = __hip_atomic_load(rp+0, __ATOMIC_RELAXED, __HIP_MEMORY_SCOPE_AGENT);
      qv1 = __hip_atomic_load(rp+1, __ATOMIC_RELAXED, __HIP_MEMORY_SCOPE_AGENT);
      qv2 = __hip_atomic_load(rp+2, __ATOMIC_RELAXED, __HIP_MEMORY_SCOPE_AGENT);
      qv3 = __hip_atomic_load(rp+3, __ATOMIC_RELAXED, __HIP_MEMORY_SCOPE_AGENT);
      qv4 = __hip_atomic_load(rp+4, __ATOMIC_RELAXED, __HIP_MEMORY_SCOPE_AGENT);
      qv5 = __hip_atomic_load(rp+5, __ATOMIC_RELAXED, __HIP_MEMORY_SCOPE_AGENT);
      qv6 = __hip_atomic_load(rp+6, __ATOMIC_RELAXED, __HIP_MEMORY_SCOPE_AGENT);
      qv7 = __hip_atomic_load(rp+7, __ATOMIC_RELAXED, __HIP_MEMORY_SCOPE_AGENT);
    }
    asm volatile("s_waitcnt lgkmcnt(0)" ::: "memory");
    __builtin_amdgcn_s_barrier();          // s_ab = h(t+1) visible to all waves
  }

  // epilogue
  #pragma unroll
  for (int e = 0; e < 4; ++e) {
    const int grow = row_base + l4 * 4 + e;
    hn_out[grow * HID + c_own] = h_[e];
    cn_out[grow * HID + c_own] = c_[e];
  }
}

extern "C" void kernel_launch(void* const* d_in, const int* in_sizes, int n_in,
                              void* d_out, int out_size, void* d_ws, size_t ws_size,
                              hipStream_t stream) {
  const float* x      = (const float*)d_in[0];
  const float* h0     = (const float*)d_in[1];
  const float* c0     = (const float*)d_in[2];
  const float* mask_x = (const float*)d_in[3];
  const float* mask_h = (const float*)d_in[4];
  const float* W_ih   = (const float*)d_in[5];
  const float* W_hh   = (const float*)d_in[6];
  const float* b_ih   = (const float*)d_in[7];
  const float* b_hh   = (const float*)d_in[8];
  const int*   bs     = (const int*)d_in[9];

  float* out = (float*)d_out;
  float* hn  = out + (size_t)T_STEPS * BATCH * HID;
  float* cn  = hn + (size_t)BATCH * HID;

  int* flg  = (int*)d_ws;                          // 2 KB flags
  u64* ring = (u64*)((char*)d_ws + 16384);         // 16 x DEPTH x 8192 u64 = 4 MB

  init_ws<<<512, 256, 0, stream>>>(flg, ring);
  lstm_w16<<<32, 1024, 0, stream>>>(x, h0, c0, mask_x, mask_h, W_ih, W_hh,
                                    b_ih, b_hh, bs, out, hn, cn, flg, ring);
}

// Round 11
// 2079.474 us; speedup vs baseline: 4.6949x; 4.6949x over previous
//
#include <hip/hip_runtime.h>
#include <hip/hip_bf16.h>

#define T_STEPS 512
#define BATCH   256
#define DIM     256
#define HID     256
#define DEPTH   4    // X_proj ring depth (power of 2)

using bf16x8  = __attribute__((ext_vector_type(8))) __bf16;
using floatx4 = __attribute__((ext_vector_type(4))) float;
typedef unsigned long long u64;
typedef unsigned int u32;

__device__ __forceinline__ float sigf(float x)   { return 1.0f / (1.0f + __expf(-x)); }
__device__ __forceinline__ float tanh_f(float x) { return 1.0f - 2.0f / (1.0f + __expf(2.0f * x)); }

__device__ __forceinline__ bf16x8 cvt8(const float* p) {
  floatx4 a = *(const floatx4*)p;
  floatx4 b = *(const floatx4*)(p + 4);
  bf16x8 r;
  r[0]=(__bf16)a[0]; r[1]=(__bf16)a[1]; r[2]=(__bf16)a[2]; r[3]=(__bf16)a[3];
  r[4]=(__bf16)b[0]; r[5]=(__bf16)b[1]; r[6]=(__bf16)b[2]; r[7]=(__bf16)b[3];
  return r;
}
__device__ __forceinline__ u32 f2bf(float f) {
  union { float f; u32 u; } v; v.f = f;
  u32 lsb = (v.u >> 16) & 1;
  return (v.u + 0x7fff + lsb) >> 16;
}
__device__ __forceinline__ float bf2f(u32 u) {
  union { u32 u; float f; } v; v.u = (u & 0xffffu) << 16; return v.f;
}

__global__ void init_ws(int* __restrict__ flg, u64* __restrict__ inbox) {
  const int idx = blockIdx.x * 256 + threadIdx.x;
  if (idx < 4096) flg[idx] = 0;
  if (idx < 65536) inbox[idx] = 0ull;
}

// 64 WGs x 512 thr. blockIdx = g + 16*role; group g = 16 batch rows.
// role 0,1: consumers (h-cols [128p,128p+128), W_hh resident, static idx).
// role 2,3: producers (X_proj f32 ring, flag-gated, W_ih resident).
// Consumer: r8 skeleton + (a) out buffered in LDS, flushed 1/8 steps,
// (b) explicit vmcnt(0) drain placed in the packet-flight slack so the
// blocking inbox poll always starts with an EMPTY vmem queue.
__global__ __launch_bounds__(512, 1) void lstm_v11(
    const float* __restrict__ x, const float* __restrict__ h0,
    const float* __restrict__ c0,
    const float* __restrict__ mask_x, const float* __restrict__ mask_h,
    const float* __restrict__ W_ih, const float* __restrict__ W_hh,
    const float* __restrict__ b_ih, const float* __restrict__ b_hh,
    const int* __restrict__ bs_g,
    float* __restrict__ out, float* __restrict__ hn_out, float* __restrict__ cn_out,
    int* __restrict__ flg, float* __restrict__ ring, u64* __restrict__ inbox) {

  const int tid  = threadIdx.x;
  const int g    = blockIdx.x & 15;
  const int role = blockIdx.x >> 4;
  const int p    = role & 1;
  const int row_base = g * 16;
  const int lane = tid & 63;
  const int w    = tid >> 6;     // wave 0..7
  const int l15  = lane & 15;
  const int l4   = lane >> 4;

  __shared__ alignas(16) __bf16 s_ab[16 * 256];      // 8 KB swizzled
  __shared__ alignas(16) floatx4 s_ob[8 * 512];      // 64 KB out stash (consumer only)
  __shared__ int s_bs[T_STEPS];
  for (int i = tid; i < T_STEPS; i += 512) s_bs[i] = bs_g[i];
  __syncthreads();

  int* cons_flg_mine = flg + (g * 2 + p) * 32;          // ring backpressure
  int* prod_flg_mine = flg + 2048 + (g * 2 + p) * 32;   // ring ready
  float* ring_mine   = ring + (size_t)(g * 2 + p) * (DEPTH * 8192);
  u64* inbox_mine    = inbox + (size_t)(g * 2 + p) * 2048;       // I read here
  u64* inbox_partner = inbox + (size_t)(g * 2 + (1 - p)) * 2048; // I write here

  const int c_loc = w * 16 + l15;          // local col within the 128-col half

  if (role >= 2) {
    // ================= PRODUCER =================
    bf16x8 wih_r[4][8];
    #pragma unroll
    for (int q = 0; q < 4; ++q) {
      const size_t wr = (size_t)(q * HID + p * 128 + c_loc) * DIM;
      #pragma unroll
      for (int m = 0; m < 8; ++m) wih_r[q][m] = cvt8(W_ih + wr + m * 32 + l4 * 8);
    }
    float bias[4];
    #pragma unroll
    for (int q = 0; q < 4; ++q) {
      const int bc = q * HID + p * 128 + c_loc;
      bias[q] = b_ih[bc] + b_hh[bc];
    }
    const int srow = tid & 15, scb = (tid >> 4) * 8;
    floatx4 mx0 = *(const floatx4*)(mask_x + (row_base + srow) * DIM + scb);
    floatx4 mx1 = *(const floatx4*)(mask_x + (row_base + srow) * DIM + scb + 4);
    const int soff = (srow * 512 + scb * 2) ^ ((srow & 7) << 4);

    // prologue x(0) prefetch
    floatx4 xa, xb;
    {
      const float* xp = x + (size_t)(row_base + srow) * DIM + scb;
      xa = *(const floatx4*)xp; xb = *(const floatx4*)(xp + 4);
    }

    for (int t = 0; t < T_STEPS; ++t) {
      if (s_bs[t] <= row_base) break;
      if (t >= DEPTH) {
        const int tgt = t - (DEPTH - 1);
        while (__hip_atomic_load(cons_flg_mine, __ATOMIC_RELAXED, __HIP_MEMORY_SCOPE_AGENT) < tgt) {}
      }
      bf16x8 xv;
      #pragma unroll
      for (int e = 0; e < 4; ++e) { xv[e] = (__bf16)(xa[e] * mx0[e]); xv[4 + e] = (__bf16)(xb[e] * mx1[e]); }
      *(bf16x8*)((char*)s_ab + soff) = xv;
      asm volatile("s_waitcnt lgkmcnt(0)" ::: "memory");
      __builtin_amdgcn_s_barrier();

      floatx4 a0, a1, a2, a3;
      a0 = a1 = a2 = a3 = (floatx4)(0.0f);
      #pragma unroll
      for (int m = 0; m < 8; ++m) {
        const int ab = (l15 * 512 + l4 * 16 + m * 64) ^ ((l15 & 7) << 4);
        bf16x8 ax = *(const bf16x8*)((const char*)s_ab + ab);
        a0 = __builtin_amdgcn_mfma_f32_16x16x32_bf16(ax, wih_r[0][m], a0, 0, 0, 0);
        a1 = __builtin_amdgcn_mfma_f32_16x16x32_bf16(ax, wih_r[1][m], a1, 0, 0, 0);
        a2 = __builtin_amdgcn_mfma_f32_16x16x32_bf16(ax, wih_r[2][m], a2, 0, 0, 0);
        a3 = __builtin_amdgcn_mfma_f32_16x16x32_bf16(ax, wih_r[3][m], a3, 0, 0, 0);
      }
      // prefetch x(t+1)
      if (t + 1 < T_STEPS) {
        const float* xp = x + ((size_t)(t + 1) * BATCH + row_base + srow) * DIM + scb;
        xa = *(const floatx4*)xp; xb = *(const floatx4*)(xp + 4);
      }
      float* rs = ring_mine + (size_t)(t & (DEPTH - 1)) * 8192;
      #pragma unroll
      for (int e = 0; e < 4; ++e) {
        const int rb = (l4 * 4 + e) * 4;
        __hip_atomic_store(rs + (rb + 0) * 128 + c_loc, a0[e] + bias[0], __ATOMIC_RELAXED, __HIP_MEMORY_SCOPE_AGENT);
        __hip_atomic_store(rs + (rb + 1) * 128 + c_loc, a1[e] + bias[1], __ATOMIC_RELAXED, __HIP_MEMORY_SCOPE_AGENT);
        __hip_atomic_store(rs + (rb + 2) * 128 + c_loc, a2[e] + bias[2], __ATOMIC_RELAXED, __HIP_MEMORY_SCOPE_AGENT);
        __hip_atomic_store(rs + (rb + 3) * 128 + c_loc, a3[e] + bias[3], __ATOMIC_RELAXED, __HIP_MEMORY_SCOPE_AGENT);
      }
      asm volatile("s_waitcnt vmcnt(0)" ::: "memory");
      __builtin_amdgcn_s_barrier();
      if (tid == 0)
        __hip_atomic_store(prod_flg_mine, t + 1, __ATOMIC_RELAXED, __HIP_MEMORY_SCOPE_AGENT);
    }
    return;
  }

  // ================= CONSUMER =================
  const int c_own = p * 128 + c_loc;
  // whh_r[q][0..3] = OWN K-half, [q][4..7] = PARTNER K-half (static indices).
  bf16x8 whh_r[4][8];
  #pragma unroll
  for (int q = 0; q < 4; ++q) {
    const size_t wr = (size_t)(q * HID + c_own) * HID;
    const float* wown = W_hh + wr + p * 128;
    const float* wpar = W_hh + wr + (1 - p) * 128;
    #pragma unroll
    for (int i = 0; i < 4; ++i) {
      whh_r[q][i]     = cvt8(wown + i * 32 + l4 * 8);
      whh_r[q][4 + i] = cvt8(wpar + i * 32 + l4 * 8);
    }
  }
  float mh_c[4], h_[4], c_[4];
  #pragma unroll
  for (int e = 0; e < 4; ++e) {
    const int grow = row_base + l4 * 4 + e;
    mh_c[e] = mask_h[grow * HID + c_own];
    h_[e]   = h0[grow * HID + c_own];
    c_[e]   = c0[grow * HID + c_own];
  }
  const int sc_loc = tid >> 2;
  const int rq     = tid & 3;
  const int c_gs   = (1 - p) * 128 + sc_loc;
  float mh_s[4];
  #pragma unroll
  for (int e = 0; e < 4; ++e) mh_s[e] = mask_h[(row_base + rq * 4 + e) * HID + c_gs];

  const int abase   = l15 * 512 + l4 * 16;
  const int own_off = p * 256;
  const int par_off = (1 - p) * 256;

  // prologue: stage own h(0); preload X_proj(0)
  #pragma unroll
  for (int e = 0; e < 4; ++e) {
    const int r = l4 * 4 + e;
    const int off = (r * 512 + c_own * 2) ^ ((r & 7) << 4);
    *(__bf16*)((char*)s_ab + off) = (__bf16)(h_[e] * mh_c[e]);
  }
  while (__hip_atomic_load(prod_flg_mine, __ATOMIC_RELAXED, __HIP_MEMORY_SCOPE_AGENT) < 1) {}
  asm volatile("" ::: "memory");
  float xp_c[16];
  #pragma unroll
  for (int e = 0; e < 4; ++e)
    #pragma unroll
    for (int q = 0; q < 4; ++q)
      xp_c[e * 4 + q] = __hip_atomic_load(ring_mine + ((l4 * 4 + e) * 4 + q) * 128 + c_loc,
                                          __ATOMIC_RELAXED, __HIP_MEMORY_SCOPE_AGENT);
  asm volatile("s_waitcnt vmcnt(0) lgkmcnt(0)" ::: "memory");   // start loop with clean queue
  __builtin_amdgcn_s_barrier();

  for (int t = 0; t < T_STEPS; ++t) {
    const int bszt = s_bs[t];
    if (bszt <= row_base) {
      // retired (uniform across both consumers + producer): stash zeros (ds only)
      floatx4 z; z[0]=z[1]=z[2]=z[3]=0.0f;
      s_ob[(t & 7) * 512 + tid] = z;
      if ((t & 7) == 7) {
        const int t0 = t - 7;
        #pragma unroll
        for (int k = 0; k < 8; ++k) {
          floatx4 v = s_ob[k * 512 + tid];
          #pragma unroll
          for (int e = 0; e < 4; ++e)
            out[(size_t)(t0 + k) * (BATCH * HID) + (row_base + l4 * 4 + e) * HID + c_own] = v[e];
        }
      }
      continue;
    }
    const bool act_n = (t + 1 < T_STEPS) && (s_bs[t + 1] > row_base);

    // A: own-half MFMAs (K=128, static indices) — overlap packet flight
    floatx4 a0, a1, a2, a3;
    a0 = a1 = a2 = a3 = (floatx4)(0.0f);
    #pragma unroll
    for (int i = 0; i < 4; ++i) {
      const int ab = (abase + own_off + i * 64) ^ ((l15 & 7) << 4);
      bf16x8 ah = *(const bf16x8*)((const char*)s_ab + ab);
      a0 = __builtin_amdgcn_mfma_f32_16x16x32_bf16(ah, whh_r[0][i], a0, 0, 0, 0);
      a1 = __builtin_amdgcn_mfma_f32_16x16x32_bf16(ah, whh_r[1][i], a1, 0, 0, 0);
      a2 = __builtin_amdgcn_mfma_f32_16x16x32_bf16(ah, whh_r[2][i], a2, 0, 0, 0);
      a3 = __builtin_amdgcn_mfma_f32_16x16x32_bf16(ah, whh_r[3][i], a3, 0, 0, 0);
    }

    // B: partner half — the ONLY blocking poll, and the queue is EMPTY here
    if (t == 0) {
      #pragma unroll
      for (int e = 0; e < 4; ++e) {
        const int r = rq * 4 + e;
        const float hv = h0[(row_base + r) * HID + c_gs] * mh_s[e];
        const int off = (r * 512 + c_gs * 2) ^ ((r & 7) << 4);
        *(__bf16*)((char*)s_ab + off) = (__bf16)hv;
      }
    } else {
      const u64* ib = inbox_mine + (size_t)(t & 1) * 1024 + sc_loc * 8 + rq * 2;
      u64 pk0, pk1;
      do {
        pk0 = __hip_atomic_load(ib,     __ATOMIC_RELAXED, __HIP_MEMORY_SCOPE_AGENT);
        pk1 = __hip_atomic_load(ib + 1, __ATOMIC_RELAXED, __HIP_MEMORY_SCOPE_AGENT);
      } while (!__all((int)(((u32)pk0 == (u32)t) && ((u32)pk1 == (u32)t))));
      float hv[4];
      hv[0] = bf2f((u32)(pk0 >> 32)) * mh_s[0];
      hv[1] = bf2f((u32)(pk0 >> 48)) * mh_s[1];
      hv[2] = bf2f((u32)(pk1 >> 32)) * mh_s[2];
      hv[3] = bf2f((u32)(pk1 >> 48)) * mh_s[3];
      #pragma unroll
      for (int e = 0; e < 4; ++e) {
        const int r = rq * 4 + e;
        const int off = (r * 512 + c_gs * 2) ^ ((r & 7) << 4);
        *(__bf16*)((char*)s_ab + off) = (__bf16)hv[e];
      }
    }
    asm volatile("s_waitcnt lgkmcnt(0)" ::: "memory");
    __builtin_amdgcn_s_barrier();   // partner region visible

    // C: partner-half MFMAs (K=128, static indices 4..7)
    #pragma unroll
    for (int i = 0; i < 4; ++i) {
      const int ab = (abase + par_off + i * 64) ^ ((l15 & 7) << 4);
      bf16x8 ah = *(const bf16x8*)((const char*)s_ab + ab);
      a0 = __builtin_amdgcn_mfma_f32_16x16x32_bf16(ah, whh_r[0][4 + i], a0, 0, 0, 0);
      a1 = __builtin_amdgcn_mfma_f32_16x16x32_bf16(ah, whh_r[1][4 + i], a1, 0, 0, 0);
      a2 = __builtin_amdgcn_mfma_f32_16x16x32_bf16(ah, whh_r[2][4 + i], a2, 0, 0, 0);
      a3 = __builtin_amdgcn_mfma_f32_16x16x32_bf16(ah, whh_r[3][4 + i], a3, 0, 0, 0);
    }

    // D: cell (C layout: row = l4*4+e, col = l15 -> c_own)
    floatx4 o4;
    #pragma unroll
    for (int e = 0; e < 4; ++e) {
      const bool ract = (row_base + l4 * 4 + e) < bszt;
      const float iv = sigf(a0[e] + xp_c[e * 4 + 0]);
      const float fv = sigf(a1[e] + xp_c[e * 4 + 1]);
      const float gv = tanh_f(a2[e] + xp_c[e * 4 + 2]);
      const float ov = sigf(a3[e] + xp_c[e * 4 + 3]);
      const float cc = fv * c_[e] + iv * gv;
      const float hh = ov * tanh_f(cc);
      if (ract) { c_[e] = cc; h_[e] = hh; }
      o4[e] = ract ? hh : 0.0f;
    }

    // E: SEND FIRST — partner's flight starts now
    if (act_n) {
      u64* ob = inbox_partner + (size_t)((t + 1) & 1) * 1024 + c_loc * 8 + l4 * 2;
      const u64 tag = (u32)(t + 1);
      u64 w0 = tag | ((u64)f2bf(h_[0]) << 32) | ((u64)f2bf(h_[1]) << 48);
      u64 w1 = tag | ((u64)f2bf(h_[2]) << 32) | ((u64)f2bf(h_[3]) << 48);
      __hip_atomic_store(ob,     w0, __ATOMIC_RELAXED, __HIP_MEMORY_SCOPE_AGENT);
      __hip_atomic_store(ob + 1, w1, __ATOMIC_RELAXED, __HIP_MEMORY_SCOPE_AGENT);
    }

    // F (slack window, all latency hidden under partner flight):
    //    own-h(t+1) staging (ds), out -> stash (ds), 1/8 flush (HBM),
    //    cons_flg, ring loads for X_proj(t+1), then vmcnt(0) drain.
    if (act_n) {
      #pragma unroll
      for (int e = 0; e < 4; ++e) {
        const int r = l4 * 4 + e;
        const int off = (r * 512 + c_own * 2) ^ ((r & 7) << 4);
        *(__bf16*)((char*)s_ab + off) = (__bf16)(h_[e] * mh_c[e]);
      }
    }
    s_ob[(t & 7) * 512 + tid] = o4;
    if ((t & 7) == 7) {
      const int t0 = t - 7;
      #pragma unroll
      for (int k = 0; k < 8; ++k) {
        floatx4 v = s_ob[k * 512 + tid];
        #pragma unroll
        for (int e = 0; e < 4; ++e)
          out[(size_t)(t0 + k) * (BATCH * HID) + (row_base + l4 * 4 + e) * HID + c_own] = v[e];
      }
    }
    if (act_n) {
      if (tid == 0)
        __hip_atomic_store(cons_flg_mine, t + 1, __ATOMIC_RELAXED, __HIP_MEMORY_SCOPE_AGENT);
      while (__hip_atomic_load(prod_flg_mine, __ATOMIC_RELAXED, __HIP_MEMORY_SCOPE_AGENT) < t + 2) {}
      asm volatile("" ::: "memory");
      const float* rs = ring_mine + (size_t)((t + 1) & (DEPTH - 1)) * 8192;
      #pragma unroll
      for (int e = 0; e < 4; ++e)
        #pragma unroll
        for (int q = 0; q < 4; ++q)
          xp_c[e * 4 + q] = __hip_atomic_load(rs + ((l4 * 4 + e) * 4 + q) * 128 + c_loc,
                                              __ATOMIC_RELAXED, __HIP_MEMORY_SCOPE_AGENT);
    }
    // drain EVERYTHING now, inside the slack — next poll starts clean
    asm volatile("s_waitcnt vmcnt(0) lgkmcnt(0)" ::: "memory");
    __builtin_amdgcn_s_barrier();   // own-h(t+1) visible; WAR-protect s_ab
  }

  // epilogue
  #pragma unroll
  for (int e = 0; e < 4; ++e) {
    const int grow = row_base + l4 * 4 + e;
    hn_out[grow * HID + c_own] = h_[e];
    cn_out[grow * HID + c_own] = c_[e];
  }
}

extern "C" void kernel_launch(void* const* d_in, const int* in_sizes, int n_in,
                              void* d_out, int out_size, void* d_ws, size_t ws_size,
                              hipStream_t stream) {
  const float* x      = (const float*)d_in[0];
  const float* h0     = (const float*)d_in[1];
  const float* c0     = (const float*)d_in[2];
  const float* mask_x = (const float*)d_in[3];
  const float* mask_h = (const float*)d_in[4];
  const float* W_ih   = (const float*)d_in[5];
  const float* W_hh   = (const float*)d_in[6];
  const float* b_ih   = (const float*)d_in[7];
  const float* b_hh   = (const float*)d_in[8];
  const int*   bs     = (const int*)d_in[9];

  float* out = (float*)d_out;
  float* hn  = out + (size_t)T_STEPS * BATCH * HID;
  float* cn  = hn + (size_t)BATCH * HID;

  int* flg   = (int*)d_ws;                                  // 16 KB flags
  float* ring = (float*)((char*)d_ws + 16384);              // 4 MB X_proj ring
  u64* inbox = (u64*)((char*)d_ws + 16384 + 4194304);       // 512 KB packet inboxes

  init_ws<<<256, 256, 0, stream>>>(flg, inbox);
  lstm_v11<<<64, 512, 0, stream>>>(x, h0, c0, mask_x, mask_h, W_ih, W_hh,
                                   b_ih, b_hh, bs, out, hn, cn, flg, ring, inbox);
}